// Round 15
// baseline (1957.273 us; speedup 1.0000x reference)
//
#include <hip/hip_runtime.h>
#include <hip/hip_bf16.h>
#include <math.h>

// ---------------------------------------------------------------------------
// MultiScaleVQVAE forward (scale_idx==2).
//   recon [8,1,256,256] | z_q [8,256,64,64] | indices [8,64,64] (as float)
// Encoder + VQ: fp32, accumulation order frozen (indices must match numpy's
// fp32 argmin near-bitwise; np pairwise-sum norms emulated).
// Decoder: bf16 MFMA (threshold 20.48 makes decoder numerics uncritical).
// R15: vq back to single kernel (split was occupancy-neutral) with float4
// ct reads (ct padded [64][68]; k-ascending order preserved -> dist bits
// identical); conv_out 32x32 tile, 4 px/thread.
// ---------------------------------------------------------------------------

#define NB 8  // batch

typedef short v8s __attribute__((ext_vector_type(8)));
typedef float v4f __attribute__((ext_vector_type(4)));

// ---- numpy pairwise sum-of-squares, n=256 (split 128+128, 8-acc blocks) ----
__device__ __forceinline__ float sumsq128(const float* __restrict__ p, int stride) {
  float r[8];
#pragma unroll
  for (int j = 0; j < 8; ++j) {
    float v = p[(size_t)j * stride];
    r[j] = __fmul_rn(v, v);
  }
  for (int i = 8; i < 128; i += 8) {
#pragma unroll
    for (int j = 0; j < 8; ++j) {
      float v = p[(size_t)(i + j) * stride];
      r[j] = __fadd_rn(r[j], __fmul_rn(v, v));
    }
  }
  return __fadd_rn(__fadd_rn(__fadd_rn(r[0], r[1]), __fadd_rn(r[2], r[3])),
                   __fadd_rn(__fadd_rn(r[4], r[5]), __fadd_rn(r[6], r[7])));
}
__device__ __forceinline__ float sumsq256(const float* __restrict__ p, int stride) {
  return __fadd_rn(sumsq128(p, stride), sumsq128(p + (size_t)128 * stride, stride));
}

// ---- FUSED conv1 + conv3s2-a (R13-proven) ----
__global__ __launch_bounds__(256) void k_conv12(const float* __restrict__ x,
                                                const float* __restrict__ ew1,
                                                const float* __restrict__ eb1,
                                                const float* __restrict__ ew2,
                                                const float* __restrict__ bias2,
                                                float* __restrict__ out) {
  const int IH = 256;
  const int OH = 128;
  const int TILES_X = OH / 16;
  int n = blockIdx.z;
  int cg = blockIdx.y;  // group of 32 c_out
  int tile = blockIdx.x;
  int OY0 = (tile / TILES_X) * 16, OX0 = (tile % TILES_X) * 16;
  int ty = threadIdx.x >> 4, tx = threadIdx.x & 15;
  int oy = OY0 + ty, ox = OX0 + tx;

  const float* xin = x + (size_t)n * IH * IH;
  float xv[5][5];
#pragma unroll
  for (int a = 0; a < 5; ++a)
#pragma unroll
    for (int b = 0; b < 5; ++b) {
      int iy = 2 * oy - 2 + a, ix = 2 * ox - 2 + b;
      xv[a][b] = (iy >= 0 && iy < IH && ix >= 0 && ix < IH) ? xin[iy * IH + ix] : 0.f;
    }

  unsigned hmask = 0;
#pragma unroll
  for (int dy = 0; dy < 3; ++dy)
#pragma unroll
    for (int dx = 0; dx < 3; ++dx) {
      int hy = 2 * oy - 1 + dy, hx = 2 * ox - 1 + dx;
      if (hy >= 0 && hy < IH && hx >= 0 && hx < IH) hmask |= 1u << (dy * 3 + dx);
    }

  float acc[32];
#pragma unroll
  for (int c = 0; c < 32; ++c) acc[c] = 0.f;

  for (int ci = 0; ci < 64; ++ci) {
    const float* w1 = ew1 + ci * 9;
    float b1 = eb1[ci];
    float v[9];
#pragma unroll
    for (int dy = 0; dy < 3; ++dy)
#pragma unroll
      for (int dx = 0; dx < 3; ++dx) {
        int k = dy * 3 + dx;
        if (hmask & (1u << k)) {
          float h = b1;
#pragma unroll
          for (int ey = 0; ey < 3; ++ey)
#pragma unroll
            for (int ex = 0; ex < 3; ++ex) h += xv[dy + ey][dx + ex] * w1[ey * 3 + ex];
          v[k] = fmaxf(h, 0.f);
        } else {
          v[k] = 0.f;
        }
      }
    const float* wp = ew2 + ((size_t)(cg * 32) * 64 + ci) * 9;
#pragma unroll
    for (int c = 0; c < 32; ++c) {
#pragma unroll
      for (int k = 0; k < 9; ++k) acc[c] += v[k] * wp[(size_t)c * 64 * 9 + k];
    }
  }
  float* ob = out + (((size_t)n * 128 + cg * 32) * OH + oy) * OH + ox;
#pragma unroll
  for (int c = 0; c < 32; ++c) {
    float r = acc[c] + bias2[cg * 32 + c];
    ob[(size_t)c * OH * OH] = fmaxf(r, 0.f);
  }
}

// ---- conv 3x3 stride 2 pad 1 + ReLU. 16x16 out tile x 32 c_out (R12). ----
template <int CI, int IH>
__global__ __launch_bounds__(256) void k_conv3s2(const float* __restrict__ in,
                                                 const float* __restrict__ w,
                                                 const float* __restrict__ bias,
                                                 float* __restrict__ out, int CO) {
  const int OH = IH / 2;
  const int TILES_X = OH / 16;
  const int RS = 40;
  int n = blockIdx.z;
  int cg = blockIdx.y;
  int tile = blockIdx.x;
  int OY0 = (tile / TILES_X) * 16, OX0 = (tile % TILES_X) * 16;
  int ty = threadIdx.x >> 4, tx = threadIdx.x & 15;
  __shared__ float sm[2][33 * RS];
  float acc[32];
#pragma unroll
  for (int c = 0; c < 32; ++c) acc[c] = 0.f;
  int iy0 = 2 * OY0 - 1, ix0 = 2 * OX0 - 1;
  const float* inb = in + (size_t)n * CI * IH * IH;

  for (int t = threadIdx.x; t < 2 * 33 * RS; t += 256) (&sm[0][0])[t] = 0.f;

  int goff[5], loff[5];
  unsigned vmask = 0;
#pragma unroll
  for (int i = 0; i < 5; ++i) {
    int t = threadIdx.x + 256 * i;
    if (t < 33 * 33) {
      int r = t / 33, c = t - r * 33;
      int iy = iy0 + r, ix = ix0 + c;
      if (iy >= 0 && iy < IH && ix >= 0 && ix < IH) {
        vmask |= 1u << i;
        goff[i] = iy * IH + ix;
        loff[i] = r * RS + (c >> 1) + (c & 1) * 17;
      }
    }
  }
  __syncthreads();

  auto stage = [&](int buf, int ci) {
    const float* ip = inb + (size_t)ci * IH * IH;
    float* dst = sm[buf];
#pragma unroll
    for (int i = 0; i < 5; ++i)
      if (vmask & (1u << i)) dst[loff[i]] = ip[goff[i]];
  };
  stage(0, 0);
  for (int ci = 0; ci < CI; ++ci) {
    int buf = ci & 1;
    __syncthreads();
    if (ci + 1 < CI) stage(buf ^ 1, ci + 1);
    float v[9];
#pragma unroll
    for (int dy = 0; dy < 3; ++dy)
#pragma unroll
      for (int dx = 0; dx < 3; ++dx)
        v[dy * 3 + dx] = sm[buf][(2 * ty + dy) * RS + (dx & 1) * 17 + tx + (dx >> 1)];
    const float* wp = w + ((size_t)(cg * 32) * CI + ci) * 9;
#pragma unroll
    for (int c = 0; c < 32; ++c) {
#pragma unroll
      for (int k = 0; k < 9; ++k) acc[c] += v[k] * wp[(size_t)c * CI * 9 + k];
    }
  }
  int oy = OY0 + ty, ox = OX0 + tx;
  float* ob = out + (((size_t)n * CO + cg * 32) * OH + oy) * OH + ox;
#pragma unroll
  for (int c = 0; c < 32; ++c) {
    float r = acc[c] + bias[cg * 32 + c];
    ob[(size_t)c * OH * OH] = fmaxf(r, 0.f);
  }
}

// ---- 1x1 conv (GEMM over pixels), fp32, 16 c_out — z producer. ----
__global__ __launch_bounds__(256) void k_conv1x1(const float* __restrict__ in,
                                                 const float* __restrict__ w,
                                                 const float* __restrict__ bias,
                                                 float* __restrict__ out, int CI, int CO,
                                                 int HW) {
  int n = blockIdx.z;
  int cg = blockIdx.y;  // group of 16 c_out
  int px = blockIdx.x * 256 + threadIdx.x;
  __shared__ float sm[16][256];
  const float* inb = in + (size_t)n * CI * HW;
  float acc[16];
#pragma unroll
  for (int c = 0; c < 16; ++c) acc[c] = 0.f;
  for (int c0 = 0; c0 < CI; c0 += 16) {
#pragma unroll
    for (int i = 0; i < 16; ++i) sm[i][threadIdx.x] = inb[(size_t)(c0 + i) * HW + px];
    __syncthreads();
    const float* wb = w + (size_t)(cg * 16) * CI + c0;
#pragma unroll
    for (int i = 0; i < 16; ++i) {
      float r = sm[i][threadIdx.x];
#pragma unroll
      for (int c = 0; c < 16; ++c) acc[c] += r * wb[(size_t)c * CI + i];
    }
    __syncthreads();
  }
#pragma unroll
  for (int c = 0; c < 16; ++c) {
    float r = acc[c] + bias[cg * 16 + c];
    out[((size_t)n * CO + cg * 16 + c) * HW + px] = r;
  }
}

// ---- codebook squared norms: numpy pairwise order ----
__global__ __launch_bounds__(256) void k_cnorm(const float* __restrict__ cb,
                                               float* __restrict__ cn) {
  int j = blockIdx.x * 256 + threadIdx.x;
  if (j < 1024) cn[j] = sumsq256(cb + (size_t)j * 256, 1);
}

// ---- per-pixel ||z||^2: numpy pairwise order ----
__global__ __launch_bounds__(256) void k_xnorm(const float* __restrict__ z,
                                               float* __restrict__ xn) {
  int t = blockIdx.x * 256 + threadIdx.x;
  int n = t >> 12, yx = t & 4095;
  xn[t] = sumsq256(z + (size_t)n * 256 * 4096 + yx, 4096);
}

// ---- fused VQ: dist GEMM + running argmin, np-fp32-faithful.
// ct padded [64][68] (16B-aligned rows) -> float4 reads of both operands;
// per-acc accumulation stays k-ascending -> dist bits identical. ----
__global__ __launch_bounds__(256) void k_vq(const float* __restrict__ z,
                                            const float* __restrict__ cb,
                                            const float* __restrict__ cn,
                                            const float* __restrict__ xn,
                                            int* __restrict__ idx,
                                            float* __restrict__ idxf) {
  __shared__ __align__(16) float zt[64][68];
  __shared__ __align__(16) float ct[64][68];
  __shared__ float cnt[64];
  __shared__ float xnt[64];
  __shared__ float rbest[64][17];
  __shared__ int ribest[64][17];
  int tid = threadIdx.x;
  int pq = tid & 15;
  int cq = tid >> 4;
  int p0 = blockIdx.x * 64;
  int n = p0 >> 12;
  int yx0 = p0 & 4095;
  const float* zb = z + (size_t)n * 256 * 4096 + yx0;
  if (tid < 64) xnt[tid] = xn[p0 + tid];
  float best[4] = {3.0e38f, 3.0e38f, 3.0e38f, 3.0e38f};
  int bidx[4] = {0, 0, 0, 0};
  for (int c0 = 0; c0 < 1024; c0 += 64) {
    float acc[4][4];
#pragma unroll
    for (int a = 0; a < 4; ++a)
#pragma unroll
      for (int b = 0; b < 4; ++b) acc[a][b] = 0.f;
    for (int k0 = 0; k0 < 256; k0 += 64) {
      __syncthreads();
      for (int t = tid; t < 4096; t += 256) {
        int r = t >> 6, c = t & 63;
        zt[r][c] = zb[(size_t)(k0 + r) * 4096 + c];
      }
      for (int t = tid; t < 4096; t += 256) {
        int c = t >> 6, r = t & 63;
        ct[c][r] = cb[(size_t)(c0 + c) * 256 + k0 + r];
      }
      if (k0 == 0 && tid < 64) cnt[tid] = cn[c0 + tid];
      __syncthreads();
#pragma unroll 4
      for (int k = 0; k < 64; k += 4) {
        float4 za[4];
#pragma unroll
        for (int i = 0; i < 4; ++i) za[i] = *(const float4*)&zt[k + i][pq * 4];
        float4 cv[4];
#pragma unroll
        for (int j = 0; j < 4; ++j) cv[j] = *(const float4*)&ct[cq * 4 + j][k];
#pragma unroll
        for (int i = 0; i < 4; ++i) {
#pragma unroll
          for (int j = 0; j < 4; ++j) {
            float cvi = (i == 0) ? cv[j].x : (i == 1) ? cv[j].y : (i == 2) ? cv[j].z : cv[j].w;
            acc[0][j] += za[i].x * cvi;
            acc[1][j] += za[i].y * cvi;
            acc[2][j] += za[i].z * cvi;
            acc[3][j] += za[i].w * cvi;
          }
        }
      }
    }
#pragma unroll
    for (int pi = 0; pi < 4; ++pi) {
      float xnp = xnt[pq * 4 + pi];
#pragma unroll
      for (int j = 0; j < 4; ++j) {
        float A = __fadd_rn(xnp, cnt[cq * 4 + j]);
        float d = __fsub_rn(A, __fmul_rn(2.0f, acc[pi][j]));
        if (d < best[pi]) {
          best[pi] = d;
          bidx[pi] = c0 + cq * 4 + j;
        }
      }
    }
  }
  __syncthreads();
#pragma unroll
  for (int pi = 0; pi < 4; ++pi) {
    rbest[pq * 4 + pi][cq] = best[pi];
    ribest[pq * 4 + pi][cq] = bidx[pi];
  }
  __syncthreads();
  if (tid < 64) {
    float bv = rbest[tid][0];
    int bj = ribest[tid][0];
    for (int g = 1; g < 16; ++g) {
      float v = rbest[tid][g];
      int j2 = ribest[tid][g];
      if (v < bv || (v == bv && j2 < bj)) { bv = v; bj = j2; }
    }
    idx[p0 + tid] = bj;
    idxf[p0 + tid] = (float)bj;
  }
}

// ---- gather: z_q (fp32, d_out) + bf16 copy for decoder (ws) ----
__global__ __launch_bounds__(256) void k_gather(const int* __restrict__ idx,
                                                const float* __restrict__ cb,
                                                float* __restrict__ zq,
                                                __hip_bfloat16* __restrict__ zqbf) {
  size_t t = (size_t)blockIdx.x * 256 + threadIdx.x;
  int yx = (int)(t & 4095);
  int d = (int)((t >> 12) & 255);
  int n = (int)(t >> 20);
  int p = (n << 12) | yx;
  float v = cb[(size_t)idx[p] * 256 + d];
  zq[t] = v;
  zqbf[t] = __float2bfloat16(v);
}

// ---- weight transform for MFMA convT ----
__global__ __launch_bounds__(256) void k_wconv(const float* __restrict__ w,
                                               __hip_bfloat16* __restrict__ wA,
                                               int CI, int CO) {
  int t = blockIdx.x * 256 + threadIdx.x;
  int total = 4 * CO * CI * 4;
  if (t >= total) return;
  int tap = t & 3;
  int q = t >> 2;
  int ci = q % CI;
  int pc = q / CI;
  int co = pc % CO;
  int par = pc / CO;
  int a = tap >> 1, b = tap & 1, ry = par >> 1, rx = par & 1;
  float v = w[((size_t)ci * CO + co) * 16 + (3 - ry - 2 * a) * 4 + (3 - rx - 2 * b)];
  wA[t] = __float2bfloat16(v);
}

// ---- dw1 [co][ci] fp32 -> bf16 ----
__global__ __launch_bounds__(256) void k_wconv1(const float* __restrict__ w,
                                                __hip_bfloat16* __restrict__ wb) {
  int t = blockIdx.x * 256 + threadIdx.x;
  if (t < 65536) wb[t] = __float2bfloat16(w[t]);
}

// ---- d1: 1x1 conv 256->256 + ReLU via bf16 MFMA ----
__global__ __launch_bounds__(256) void k_d1mfma(const __hip_bfloat16* __restrict__ in,
                                                const __hip_bfloat16* __restrict__ wb,
                                                const float* __restrict__ bias,
                                                __hip_bfloat16* __restrict__ out) {
  int n = blockIdx.z;
  int co0 = blockIdx.y * 64;
  int px0 = blockIdx.x * 64;
  int tid = threadIdx.x;
  int w = tid >> 6, lane = tid & 63, fr = lane & 15, kg = lane >> 4;

  __shared__ __align__(16) ushort Wt[64][40];
  __shared__ __align__(16) ushort Zt[64][40];

  v4f acc[4];
#pragma unroll
  for (int q = 0; q < 4; ++q) acc[q] = (v4f){0.f, 0.f, 0.f, 0.f};

  const ushort* inb = (const ushort*)in + (size_t)n * 256 * 4096;
  const ushort* wab = (const ushort*)wb;

  for (int k0 = 0; k0 < 256; k0 += 32) {
    __syncthreads();
    {
      int co = tid & 63, kgg = tid >> 6;
      const uint4 v = *(const uint4*)(wab + (size_t)(co0 + co) * 256 + k0 + kgg * 8);
      *(uint4*)&Wt[co][kgg * 8] = v;
    }
    {
      int ci = tid >> 3, pxg = tid & 7;
      const ushort* src = inb + (size_t)(k0 + ci) * 4096 + px0 + pxg * 8;
      uint4 v = *(const uint4*)src;
      const ushort* vs = (const ushort*)&v;
#pragma unroll
      for (int j = 0; j < 8; ++j) Zt[pxg * 8 + j][ci] = vs[j];
    }
    __syncthreads();
    v8s af = *(const v8s*)&Wt[w * 16 + fr][kg * 8];
#pragma unroll
    for (int q = 0; q < 4; ++q) {
      v8s b = *(const v8s*)&Zt[q * 16 + fr][kg * 8];
      acc[q] = __builtin_amdgcn_mfma_f32_16x16x32_bf16(af, b, acc[q], 0, 0, 0);
    }
  }
  __hip_bfloat16* ob = out + (size_t)n * 256 * 4096;
#pragma unroll
  for (int q = 0; q < 4; ++q) {
    int px = px0 + q * 16 + fr;
#pragma unroll
    for (int r = 0; r < 4; ++r) {
      int co = co0 + w * 16 + kg * 4 + r;
      float val = fmaxf(acc[q][r] + bias[co], 0.f);
      ob[(size_t)co * 4096 + px] = __float2bfloat16(val);
    }
  }
}

// ---- ConvT k4 s2 p1 + ReLU via bf16 MFMA (implicit GEMM). ----
template <int CI, int IH, int CO>
__global__ __launch_bounds__(256) void k_convTmfma(const __hip_bfloat16* __restrict__ in,
                                                   const __hip_bfloat16* __restrict__ wA,
                                                   const float* __restrict__ bias,
                                                   __hip_bfloat16* __restrict__ out) {
  const int OH = 2 * IH;
  const int NT = IH / 32;
  int n = blockIdx.z;
  int co0 = blockIdx.y * 64;
  int m = blockIdx.x / NT;
  int n0x = (blockIdx.x % NT) * 32;
  int tid = threadIdx.x;
  int w = tid >> 6, lane = tid & 63, fr = lane & 15, kg = lane >> 4;

  __shared__ __align__(16) ushort Wt[4][64][40];
  __shared__ __align__(16) ushort Bt[4][32][40];
  __shared__ ushort patch[8][3][36];

  v4f acc[4][2];
#pragma unroll
  for (int p = 0; p < 4; ++p)
#pragma unroll
    for (int h = 0; h < 2; ++h) acc[p][h] = (v4f){0.f, 0.f, 0.f, 0.f};

  const ushort* inb = (const ushort*)in + (size_t)n * CI * IH * IH;
  const ushort* wab = (const ushort*)wA;

  for (int t = tid; t < 8 * 3 * 36; t += 256) (&patch[0][0][0])[t] = 0;

  int pgoff[4], ploff[4];
  unsigned pmask = 0;
#pragma unroll
  for (int i = 0; i < 4; ++i) {
    int t = tid + 256 * i;
    if (t < 816) {
      int ci = t / 102;
      int rem = t - ci * 102;
      int r = rem / 34;
      int c = rem - r * 34;
      int iy = m - 1 + r, ix = n0x - 1 + c;
      if (iy >= 0 && iy < IH && ix >= 0 && ix < IH) {
        pmask |= 1u << i;
        pgoff[i] = (ci * IH + iy) * IH + ix;
        ploff[i] = (ci * 3 + r) * 36 + c;
      }
    }
  }

  for (int ci0 = 0; ci0 < CI; ci0 += 8) {
    __syncthreads();
    {
      const ushort* ip = inb + (size_t)ci0 * IH * IH;
      ushort* pb = &patch[0][0][0];
#pragma unroll
      for (int i = 0; i < 4; ++i)
        if (pmask & (1u << i)) pb[ploff[i]] = ip[pgoff[i]];
    }
#pragma unroll
    for (int i = 0; i < 4; ++i) {
      int u = tid + 256 * i;
      int kgg = u & 3, co = (u >> 2) & 63, par = u >> 8;
      const uint4 v =
          *(const uint4*)(wab + (((size_t)par * CO + co0 + co) * CI + ci0) * 4 + kgg * 8);
      *(uint4*)&Wt[par][co][kgg * 8] = v;
    }
    __syncthreads();
    {
      int pr = tid >> 1;
      int px0 = (tid & 1) * 16;
      int par = pr >> 5, k = pr & 31;
      int ci = k >> 2, a = (k >> 1) & 1, b = k & 1, ry = par >> 1, rx = par & 1;
      const ushort* src = &patch[ci][ry + a][px0 + rx + b];
      ushort* dst = &Bt[par][px0][k];
#pragma unroll
      for (int p = 0; p < 16; ++p) dst[p * 40] = src[p];
    }
    __syncthreads();
#pragma unroll
    for (int par = 0; par < 4; ++par) {
      v8s af = *(const v8s*)&Wt[par][w * 16 + fr][kg * 8];
      v8s b0 = *(const v8s*)&Bt[par][fr][kg * 8];
      v8s b1 = *(const v8s*)&Bt[par][16 + fr][kg * 8];
      acc[par][0] = __builtin_amdgcn_mfma_f32_16x16x32_bf16(af, b0, acc[par][0], 0, 0, 0);
      acc[par][1] = __builtin_amdgcn_mfma_f32_16x16x32_bf16(af, b1, acc[par][1], 0, 0, 0);
    }
  }
  __hip_bfloat16* ob = out + (size_t)n * CO * OH * OH;
#pragma unroll
  for (int par = 0; par < 4; ++par) {
    int ry = par >> 1, rx = par & 1;
    int oy = 2 * m + ry;
#pragma unroll
    for (int h = 0; h < 2; ++h) {
      int ox = 2 * (n0x + h * 16 + fr) + rx;
#pragma unroll
      for (int r = 0; r < 4; ++r) {
        int co = co0 + w * 16 + kg * 4 + r;
        float val = acc[par][h][r] + bias[co];
        val = fmaxf(val, 0.f);
        ob[((size_t)co * OH + oy) * OH + ox] = __float2bfloat16(val);
      }
    }
  }
}

// ---- D4: conv 64->1, 3x3, s1, p1, sigmoid; bf16 in. 32x32 tile,
// 2x2 px/thread (36 FMA/ci), 34x36 LDS dbuf, hoisted geometry. ----
__global__ __launch_bounds__(256) void k_conv_out(const __hip_bfloat16* __restrict__ in,
                                                  const float* __restrict__ w,
                                                  const float* __restrict__ bias,
                                                  float* __restrict__ out) {
  int n = blockIdx.z;
  int tile = blockIdx.x;  // 64 tiles of 32x32
  int TY0 = (tile >> 3) * 32, TX0 = (tile & 7) * 32;
  int ty = threadIdx.x >> 4, tx = threadIdx.x & 15;
  __shared__ float sm[2][34 * 36];
  float acc[4];
  float b0 = bias[0];
#pragma unroll
  for (int p = 0; p < 4; ++p) acc[p] = b0;
  const __hip_bfloat16* inb = in + (size_t)n * 64 * 65536;

  for (int t = threadIdx.x; t < 2 * 34 * 36; t += 256) (&sm[0][0])[t] = 0.f;

  int goff[5], loff[5];
  unsigned vmask = 0;
#pragma unroll
  for (int i = 0; i < 5; ++i) {
    int t = threadIdx.x + 256 * i;
    if (t < 34 * 34) {
      int r = t / 34, c = t - r * 34;
      int iy = TY0 - 1 + r, ix = TX0 - 1 + c;
      if (iy >= 0 && iy < 256 && ix >= 0 && ix < 256) {
        vmask |= 1u << i;
        goff[i] = iy * 256 + ix;
        loff[i] = r * 36 + c;
      }
    }
  }
  __syncthreads();

  auto stage = [&](int buf, int ci) {
    const __hip_bfloat16* ip = inb + (size_t)ci * 65536;
    float* dst = sm[buf];
#pragma unroll
    for (int i = 0; i < 5; ++i)
      if (vmask & (1u << i)) dst[loff[i]] = __bfloat162float(ip[goff[i]]);
  };
  stage(0, 0);
  for (int ci = 0; ci < 64; ++ci) {
    int buf = ci & 1;
    __syncthreads();
    if (ci + 1 < 64) stage(buf ^ 1, ci + 1);
    float w4[4][4];
#pragma unroll
    for (int a = 0; a < 4; ++a)
#pragma unroll
      for (int b = 0; b < 4; ++b) w4[a][b] = sm[buf][(2 * ty + a) * 36 + 2 * tx + b];
    const float* wp = w + ci * 9;
#pragma unroll
    for (int dy = 0; dy < 3; ++dy)
#pragma unroll
      for (int dx = 0; dx < 3; ++dx) {
        float wv = wp[dy * 3 + dx];
        acc[0] += w4[dy][dx] * wv;
        acc[1] += w4[dy][dx + 1] * wv;
        acc[2] += w4[dy + 1][dx] * wv;
        acc[3] += w4[dy + 1][dx + 1] * wv;
      }
  }
  float* ob = out + (size_t)n * 65536 + (TY0 + 2 * ty) * 256 + TX0 + 2 * tx;
#pragma unroll
  for (int py = 0; py < 2; ++py) {
    float2 v2;
    v2.x = 1.f / (1.f + expf(-acc[py * 2 + 0]));
    v2.y = 1.f / (1.f + expf(-acc[py * 2 + 1]));
    *reinterpret_cast<float2*>(ob + (size_t)py * 256) = v2;
  }
}

extern "C" void kernel_launch(void* const* d_in, const int* in_sizes, int n_in,
                              void* d_out, int out_size, void* d_ws, size_t ws_size,
                              hipStream_t stream) {
  const float* x = (const float*)d_in[0];
  const float* ew1 = (const float*)d_in[1];
  const float* eb1 = (const float*)d_in[2];
  const float* ew2 = (const float*)d_in[3];
  const float* eb2 = (const float*)d_in[4];
  const float* ew3 = (const float*)d_in[5];
  const float* eb3 = (const float*)d_in[6];
  const float* ew4 = (const float*)d_in[7];
  const float* eb4 = (const float*)d_in[8];
  const float* cb = (const float*)d_in[9];
  const float* dw1 = (const float*)d_in[10];
  const float* db1 = (const float*)d_in[11];
  const float* dw2 = (const float*)d_in[12];
  const float* db2 = (const float*)d_in[13];
  const float* dw3 = (const float*)d_in[14];
  const float* db3 = (const float*)d_in[15];
  const float* dw4 = (const float*)d_in[16];
  const float* db4 = (const float*)d_in[17];

  float* ws = (float*)d_ws;
  float* A = ws;
  float* Bb = ws + 33554432;
  float* Cc = ws + 50331648;
  float* cn = A + 16777216;                                   // 1024
  float* xn = A + 16778240;                                   // 32768
  int* idx = (int*)(A + 16811008);                            // 32768 ints
  __hip_bfloat16* zqbf = (__hip_bfloat16*)(A + 20971520);     // 8,388,608 bf16
  __hip_bfloat16* wbfA2 = (__hip_bfloat16*)(A + 25165824);    // 524,288 bf16
  __hip_bfloat16* wbfA3 = (__hip_bfloat16*)(A + 25427968);    // 131,072 bf16
  __hip_bfloat16* wbf1 = (__hip_bfloat16*)(A + 25493504);     // 65,536 bf16
  __hip_bfloat16* d1bf = (__hip_bfloat16*)Cc;                 // 8,388,608 bf16
  __hip_bfloat16* d2bf = (__hip_bfloat16*)Bb;                 // 16,777,216 bf16
  __hip_bfloat16* d3bf = (__hip_bfloat16*)A;                  // 33,554,432 bf16

  float* recon = (float*)d_out;               // 524,288
  float* zq = recon + 524288;                 // 8,388,608
  float* idxf = zq + 8388608;                 // 32,768

  // encoder (fp32, bit-frozen chains)
  k_conv12<<<dim3(64, 4, NB), 256, 0, stream>>>(x, ew1, eb1, ew2, eb2, Bb);
  k_conv3s2<128, 128><<<dim3(16, 8, NB), 256, 0, stream>>>(Bb, ew3, eb3, Cc, 256);
  k_conv1x1<<<dim3(16, 16, NB), 256, 0, stream>>>(Cc, ew4, eb4, A, 256, 256, 4096);
  // decoder weight transforms
  k_wconv<<<2048, 256, 0, stream>>>(dw2, wbfA2, 256, 128);
  k_wconv<<<512, 256, 0, stream>>>(dw3, wbfA3, 128, 64);
  k_wconv1<<<256, 256, 0, stream>>>(dw1, wbf1);
  // VQ (np-fp32-faithful)
  k_cnorm<<<4, 256, 0, stream>>>(cb, cn);
  k_xnorm<<<128, 256, 0, stream>>>(A, xn);
  k_vq<<<512, 256, 0, stream>>>(A, cb, cn, xn, idx, idxf);
  k_gather<<<32768, 256, 0, stream>>>(idx, cb, zq, zqbf);
  // decoder (bf16 MFMA; reads only ws buffers)
  k_d1mfma<<<dim3(64, 4, NB), 256, 0, stream>>>(zqbf, wbf1, db1, d1bf);
  k_convTmfma<256, 64, 128><<<dim3(128, 2, NB), 256, 0, stream>>>(d1bf, wbfA2, db2, d2bf);
  k_convTmfma<128, 128, 64><<<dim3(512, 1, NB), 256, 0, stream>>>(d2bf, wbfA3, db3, d3bf);
  k_conv_out<<<dim3(64, 1, NB), 256, 0, stream>>>(d3bf, dw4, db4, recon);
}

// Round 16
// 1839.325 us; speedup vs baseline: 1.0641x; 1.0641x over previous
//
#include <hip/hip_runtime.h>
#include <hip/hip_bf16.h>
#include <math.h>

// ---------------------------------------------------------------------------
// MultiScaleVQVAE forward (scale_idx==2).
//   recon [8,1,256,256] | z_q [8,256,64,64] | indices [8,64,64] (as float)
// Encoder + VQ: fp32, accumulation order frozen (indices must match numpy's
// fp32 argmin near-bitwise; np pairwise-sum norms emulated).
// Decoder: bf16 MFMA (threshold 20.48 makes decoder numerics uncritical).
// R16: exact R13 configuration (best: 1845 us) — conv1x1 8-co, vq original,
// conv_out 16x16 — plus float4-vectorized gather (4 px/thread).
// ---------------------------------------------------------------------------

#define NB 8  // batch

typedef short v8s __attribute__((ext_vector_type(8)));
typedef float v4f __attribute__((ext_vector_type(4)));

// ---- numpy pairwise sum-of-squares, n=256 (split 128+128, 8-acc blocks) ----
__device__ __forceinline__ float sumsq128(const float* __restrict__ p, int stride) {
  float r[8];
#pragma unroll
  for (int j = 0; j < 8; ++j) {
    float v = p[(size_t)j * stride];
    r[j] = __fmul_rn(v, v);
  }
  for (int i = 8; i < 128; i += 8) {
#pragma unroll
    for (int j = 0; j < 8; ++j) {
      float v = p[(size_t)(i + j) * stride];
      r[j] = __fadd_rn(r[j], __fmul_rn(v, v));
    }
  }
  return __fadd_rn(__fadd_rn(__fadd_rn(r[0], r[1]), __fadd_rn(r[2], r[3])),
                   __fadd_rn(__fadd_rn(r[4], r[5]), __fadd_rn(r[6], r[7])));
}
__device__ __forceinline__ float sumsq256(const float* __restrict__ p, int stride) {
  return __fadd_rn(sumsq128(p, stride), sumsq128(p + (size_t)128 * stride, stride));
}

// ---- FUSED conv1 + conv3s2-a (R13-proven) ----
__global__ __launch_bounds__(256) void k_conv12(const float* __restrict__ x,
                                                const float* __restrict__ ew1,
                                                const float* __restrict__ eb1,
                                                const float* __restrict__ ew2,
                                                const float* __restrict__ bias2,
                                                float* __restrict__ out) {
  const int IH = 256;
  const int OH = 128;
  const int TILES_X = OH / 16;
  int n = blockIdx.z;
  int cg = blockIdx.y;  // group of 32 c_out
  int tile = blockIdx.x;
  int OY0 = (tile / TILES_X) * 16, OX0 = (tile % TILES_X) * 16;
  int ty = threadIdx.x >> 4, tx = threadIdx.x & 15;
  int oy = OY0 + ty, ox = OX0 + tx;

  const float* xin = x + (size_t)n * IH * IH;
  float xv[5][5];
#pragma unroll
  for (int a = 0; a < 5; ++a)
#pragma unroll
    for (int b = 0; b < 5; ++b) {
      int iy = 2 * oy - 2 + a, ix = 2 * ox - 2 + b;
      xv[a][b] = (iy >= 0 && iy < IH && ix >= 0 && ix < IH) ? xin[iy * IH + ix] : 0.f;
    }

  unsigned hmask = 0;
#pragma unroll
  for (int dy = 0; dy < 3; ++dy)
#pragma unroll
    for (int dx = 0; dx < 3; ++dx) {
      int hy = 2 * oy - 1 + dy, hx = 2 * ox - 1 + dx;
      if (hy >= 0 && hy < IH && hx >= 0 && hx < IH) hmask |= 1u << (dy * 3 + dx);
    }

  float acc[32];
#pragma unroll
  for (int c = 0; c < 32; ++c) acc[c] = 0.f;

  for (int ci = 0; ci < 64; ++ci) {
    const float* w1 = ew1 + ci * 9;
    float b1 = eb1[ci];
    float v[9];
#pragma unroll
    for (int dy = 0; dy < 3; ++dy)
#pragma unroll
      for (int dx = 0; dx < 3; ++dx) {
        int k = dy * 3 + dx;
        if (hmask & (1u << k)) {
          float h = b1;
#pragma unroll
          for (int ey = 0; ey < 3; ++ey)
#pragma unroll
            for (int ex = 0; ex < 3; ++ex) h += xv[dy + ey][dx + ex] * w1[ey * 3 + ex];
          v[k] = fmaxf(h, 0.f);
        } else {
          v[k] = 0.f;
        }
      }
    const float* wp = ew2 + ((size_t)(cg * 32) * 64 + ci) * 9;
#pragma unroll
    for (int c = 0; c < 32; ++c) {
#pragma unroll
      for (int k = 0; k < 9; ++k) acc[c] += v[k] * wp[(size_t)c * 64 * 9 + k];
    }
  }
  float* ob = out + (((size_t)n * 128 + cg * 32) * OH + oy) * OH + ox;
#pragma unroll
  for (int c = 0; c < 32; ++c) {
    float r = acc[c] + bias2[cg * 32 + c];
    ob[(size_t)c * OH * OH] = fmaxf(r, 0.f);
  }
}

// ---- conv 3x3 stride 2 pad 1 + ReLU. 16x16 out tile x 32 c_out (R12). ----
template <int CI, int IH>
__global__ __launch_bounds__(256) void k_conv3s2(const float* __restrict__ in,
                                                 const float* __restrict__ w,
                                                 const float* __restrict__ bias,
                                                 float* __restrict__ out, int CO) {
  const int OH = IH / 2;
  const int TILES_X = OH / 16;
  const int RS = 40;
  int n = blockIdx.z;
  int cg = blockIdx.y;
  int tile = blockIdx.x;
  int OY0 = (tile / TILES_X) * 16, OX0 = (tile % TILES_X) * 16;
  int ty = threadIdx.x >> 4, tx = threadIdx.x & 15;
  __shared__ float sm[2][33 * RS];
  float acc[32];
#pragma unroll
  for (int c = 0; c < 32; ++c) acc[c] = 0.f;
  int iy0 = 2 * OY0 - 1, ix0 = 2 * OX0 - 1;
  const float* inb = in + (size_t)n * CI * IH * IH;

  for (int t = threadIdx.x; t < 2 * 33 * RS; t += 256) (&sm[0][0])[t] = 0.f;

  int goff[5], loff[5];
  unsigned vmask = 0;
#pragma unroll
  for (int i = 0; i < 5; ++i) {
    int t = threadIdx.x + 256 * i;
    if (t < 33 * 33) {
      int r = t / 33, c = t - r * 33;
      int iy = iy0 + r, ix = ix0 + c;
      if (iy >= 0 && iy < IH && ix >= 0 && ix < IH) {
        vmask |= 1u << i;
        goff[i] = iy * IH + ix;
        loff[i] = r * RS + (c >> 1) + (c & 1) * 17;
      }
    }
  }
  __syncthreads();

  auto stage = [&](int buf, int ci) {
    const float* ip = inb + (size_t)ci * IH * IH;
    float* dst = sm[buf];
#pragma unroll
    for (int i = 0; i < 5; ++i)
      if (vmask & (1u << i)) dst[loff[i]] = ip[goff[i]];
  };
  stage(0, 0);
  for (int ci = 0; ci < CI; ++ci) {
    int buf = ci & 1;
    __syncthreads();
    if (ci + 1 < CI) stage(buf ^ 1, ci + 1);
    float v[9];
#pragma unroll
    for (int dy = 0; dy < 3; ++dy)
#pragma unroll
      for (int dx = 0; dx < 3; ++dx)
        v[dy * 3 + dx] = sm[buf][(2 * ty + dy) * RS + (dx & 1) * 17 + tx + (dx >> 1)];
    const float* wp = w + ((size_t)(cg * 32) * CI + ci) * 9;
#pragma unroll
    for (int c = 0; c < 32; ++c) {
#pragma unroll
      for (int k = 0; k < 9; ++k) acc[c] += v[k] * wp[(size_t)c * CI * 9 + k];
    }
  }
  int oy = OY0 + ty, ox = OX0 + tx;
  float* ob = out + (((size_t)n * CO + cg * 32) * OH + oy) * OH + ox;
#pragma unroll
  for (int c = 0; c < 32; ++c) {
    float r = acc[c] + bias[cg * 32 + c];
    ob[(size_t)c * OH * OH] = fmaxf(r, 0.f);
  }
}

// ---- 1x1 conv (GEMM over pixels), fp32, 8 c_out — z producer (R13 form) ----
__global__ __launch_bounds__(256) void k_conv1x1(const float* __restrict__ in,
                                                 const float* __restrict__ w,
                                                 const float* __restrict__ bias,
                                                 float* __restrict__ out, int CI, int CO,
                                                 int HW) {
  int n = blockIdx.z;
  int cg = blockIdx.y;
  int px = blockIdx.x * 256 + threadIdx.x;
  __shared__ float sm[16][256];
  const float* inb = in + (size_t)n * CI * HW;
  float acc[8];
#pragma unroll
  for (int c = 0; c < 8; ++c) acc[c] = 0.f;
  for (int c0 = 0; c0 < CI; c0 += 16) {
#pragma unroll
    for (int i = 0; i < 16; ++i) sm[i][threadIdx.x] = inb[(size_t)(c0 + i) * HW + px];
    __syncthreads();
    const float* wb = w + (size_t)(cg * 8) * CI + c0;
#pragma unroll
    for (int i = 0; i < 16; ++i) {
      float r = sm[i][threadIdx.x];
#pragma unroll
      for (int c = 0; c < 8; ++c) acc[c] += r * wb[(size_t)c * CI + i];
    }
    __syncthreads();
  }
#pragma unroll
  for (int c = 0; c < 8; ++c) {
    float r = acc[c] + bias[cg * 8 + c];
    out[((size_t)n * CO + cg * 8 + c) * HW + px] = r;
  }
}

// ---- codebook squared norms: numpy pairwise order ----
__global__ __launch_bounds__(256) void k_cnorm(const float* __restrict__ cb,
                                               float* __restrict__ cn) {
  int j = blockIdx.x * 256 + threadIdx.x;
  if (j < 1024) cn[j] = sumsq256(cb + (size_t)j * 256, 1);
}

// ---- per-pixel ||z||^2: numpy pairwise order ----
__global__ __launch_bounds__(256) void k_xnorm(const float* __restrict__ z,
                                               float* __restrict__ xn) {
  int t = blockIdx.x * 256 + threadIdx.x;
  int n = t >> 12, yx = t & 4095;
  xn[t] = sumsq256(z + (size_t)n * 256 * 4096 + yx, 4096);
}

// ---- fused VQ: dist GEMM + running argmin, np-fp32-faithful (R13 form) ----
__global__ __launch_bounds__(256) void k_vq(const float* __restrict__ z,
                                            const float* __restrict__ cb,
                                            const float* __restrict__ cn,
                                            const float* __restrict__ xn,
                                            int* __restrict__ idx,
                                            float* __restrict__ idxf) {
  __shared__ __align__(16) float zt[64][68];
  __shared__ float ct[64][65];
  __shared__ float cnt[64];
  __shared__ float xnt[64];
  __shared__ float rbest[64][17];
  __shared__ int ribest[64][17];
  int tid = threadIdx.x;
  int pq = tid & 15;
  int cq = tid >> 4;
  int p0 = blockIdx.x * 64;
  int n = p0 >> 12;
  int yx0 = p0 & 4095;
  const float* zb = z + (size_t)n * 256 * 4096 + yx0;
  if (tid < 64) xnt[tid] = xn[p0 + tid];
  float best[4] = {3.0e38f, 3.0e38f, 3.0e38f, 3.0e38f};
  int bidx[4] = {0, 0, 0, 0};
  for (int c0 = 0; c0 < 1024; c0 += 64) {
    float acc[4][4];
#pragma unroll
    for (int a = 0; a < 4; ++a)
#pragma unroll
      for (int b = 0; b < 4; ++b) acc[a][b] = 0.f;
    for (int k0 = 0; k0 < 256; k0 += 64) {
      __syncthreads();
      for (int t = tid; t < 4096; t += 256) {
        int r = t >> 6, c = t & 63;
        zt[r][c] = zb[(size_t)(k0 + r) * 4096 + c];
      }
      for (int t = tid; t < 4096; t += 256) {
        int c = t >> 6, r = t & 63;
        ct[c][r] = cb[(size_t)(c0 + c) * 256 + k0 + r];
      }
      if (k0 == 0 && tid < 64) cnt[tid] = cn[c0 + tid];
      __syncthreads();
#pragma unroll 8
      for (int k = 0; k < 64; ++k) {
        const float4 zz = *reinterpret_cast<const float4*>(&zt[k][pq * 4]);
#pragma unroll
        for (int j = 0; j < 4; ++j) {
          float cv = ct[cq * 4 + j][k];
          acc[0][j] += zz.x * cv;
          acc[1][j] += zz.y * cv;
          acc[2][j] += zz.z * cv;
          acc[3][j] += zz.w * cv;
        }
      }
    }
#pragma unroll
    for (int pi = 0; pi < 4; ++pi) {
      float xnp = xnt[pq * 4 + pi];
#pragma unroll
      for (int j = 0; j < 4; ++j) {
        float A = __fadd_rn(xnp, cnt[cq * 4 + j]);
        float d = __fsub_rn(A, __fmul_rn(2.0f, acc[pi][j]));
        if (d < best[pi]) {
          best[pi] = d;
          bidx[pi] = c0 + cq * 4 + j;
        }
      }
    }
  }
  __syncthreads();
#pragma unroll
  for (int pi = 0; pi < 4; ++pi) {
    rbest[pq * 4 + pi][cq] = best[pi];
    ribest[pq * 4 + pi][cq] = bidx[pi];
  }
  __syncthreads();
  if (tid < 64) {
    float bv = rbest[tid][0];
    int bj = ribest[tid][0];
    for (int g = 1; g < 16; ++g) {
      float v = rbest[tid][g];
      int j2 = ribest[tid][g];
      if (v < bv || (v == bv && j2 < bj)) { bv = v; bj = j2; }
    }
    idx[p0 + tid] = bj;
    idxf[p0 + tid] = (float)bj;
  }
}

// ---- gather: 4 px/thread. int4 idx load, float4 zq store, ushort4 bf16 ----
__global__ __launch_bounds__(256) void k_gather(const int* __restrict__ idx,
                                                const float* __restrict__ cb,
                                                float* __restrict__ zq,
                                                __hip_bfloat16* __restrict__ zqbf) {
  size_t g = (size_t)blockIdx.x * 256 + threadIdx.x;  // 2,097,152 groups
  int yx4 = (int)(g & 1023);          // group of 4 consecutive yx
  int d = (int)((g >> 10) & 255);
  int n = (int)(g >> 18);
  int pbase = (n << 12) | (yx4 << 2);
  int4 ii = *reinterpret_cast<const int4*>(&idx[pbase]);
  float4 v;
  v.x = cb[(size_t)ii.x * 256 + d];
  v.y = cb[(size_t)ii.y * 256 + d];
  v.z = cb[(size_t)ii.z * 256 + d];
  v.w = cb[(size_t)ii.w * 256 + d];
  size_t o = (((size_t)n * 256 + d) << 12) | (size_t)(yx4 << 2);
  *reinterpret_cast<float4*>(&zq[o]) = v;
  ushort4 bv;
  __hip_bfloat16 b0 = __float2bfloat16(v.x), b1 = __float2bfloat16(v.y);
  __hip_bfloat16 b2 = __float2bfloat16(v.z), b3 = __float2bfloat16(v.w);
  bv.x = *reinterpret_cast<ushort*>(&b0);
  bv.y = *reinterpret_cast<ushort*>(&b1);
  bv.z = *reinterpret_cast<ushort*>(&b2);
  bv.w = *reinterpret_cast<ushort*>(&b3);
  *reinterpret_cast<ushort4*>(&zqbf[o]) = bv;
}

// ---- weight transform for MFMA convT ----
__global__ __launch_bounds__(256) void k_wconv(const float* __restrict__ w,
                                               __hip_bfloat16* __restrict__ wA,
                                               int CI, int CO) {
  int t = blockIdx.x * 256 + threadIdx.x;
  int total = 4 * CO * CI * 4;
  if (t >= total) return;
  int tap = t & 3;
  int q = t >> 2;
  int ci = q % CI;
  int pc = q / CI;
  int co = pc % CO;
  int par = pc / CO;
  int a = tap >> 1, b = tap & 1, ry = par >> 1, rx = par & 1;
  float v = w[((size_t)ci * CO + co) * 16 + (3 - ry - 2 * a) * 4 + (3 - rx - 2 * b)];
  wA[t] = __float2bfloat16(v);
}

// ---- dw1 [co][ci] fp32 -> bf16 ----
__global__ __launch_bounds__(256) void k_wconv1(const float* __restrict__ w,
                                                __hip_bfloat16* __restrict__ wb) {
  int t = blockIdx.x * 256 + threadIdx.x;
  if (t < 65536) wb[t] = __float2bfloat16(w[t]);
}

// ---- d1: 1x1 conv 256->256 + ReLU via bf16 MFMA ----
__global__ __launch_bounds__(256) void k_d1mfma(const __hip_bfloat16* __restrict__ in,
                                                const __hip_bfloat16* __restrict__ wb,
                                                const float* __restrict__ bias,
                                                __hip_bfloat16* __restrict__ out) {
  int n = blockIdx.z;
  int co0 = blockIdx.y * 64;
  int px0 = blockIdx.x * 64;
  int tid = threadIdx.x;
  int w = tid >> 6, lane = tid & 63, fr = lane & 15, kg = lane >> 4;

  __shared__ __align__(16) ushort Wt[64][40];
  __shared__ __align__(16) ushort Zt[64][40];

  v4f acc[4];
#pragma unroll
  for (int q = 0; q < 4; ++q) acc[q] = (v4f){0.f, 0.f, 0.f, 0.f};

  const ushort* inb = (const ushort*)in + (size_t)n * 256 * 4096;
  const ushort* wab = (const ushort*)wb;

  for (int k0 = 0; k0 < 256; k0 += 32) {
    __syncthreads();
    {
      int co = tid & 63, kgg = tid >> 6;
      const uint4 v = *(const uint4*)(wab + (size_t)(co0 + co) * 256 + k0 + kgg * 8);
      *(uint4*)&Wt[co][kgg * 8] = v;
    }
    {
      int ci = tid >> 3, pxg = tid & 7;
      const ushort* src = inb + (size_t)(k0 + ci) * 4096 + px0 + pxg * 8;
      uint4 v = *(const uint4*)src;
      const ushort* vs = (const ushort*)&v;
#pragma unroll
      for (int j = 0; j < 8; ++j) Zt[pxg * 8 + j][ci] = vs[j];
    }
    __syncthreads();
    v8s af = *(const v8s*)&Wt[w * 16 + fr][kg * 8];
#pragma unroll
    for (int q = 0; q < 4; ++q) {
      v8s b = *(const v8s*)&Zt[q * 16 + fr][kg * 8];
      acc[q] = __builtin_amdgcn_mfma_f32_16x16x32_bf16(af, b, acc[q], 0, 0, 0);
    }
  }
  __hip_bfloat16* ob = out + (size_t)n * 256 * 4096;
#pragma unroll
  for (int q = 0; q < 4; ++q) {
    int px = px0 + q * 16 + fr;
#pragma unroll
    for (int r = 0; r < 4; ++r) {
      int co = co0 + w * 16 + kg * 4 + r;
      float val = fmaxf(acc[q][r] + bias[co], 0.f);
      ob[(size_t)co * 4096 + px] = __float2bfloat16(val);
    }
  }
}

// ---- ConvT k4 s2 p1 + ReLU via bf16 MFMA (implicit GEMM). ----
template <int CI, int IH, int CO>
__global__ __launch_bounds__(256) void k_convTmfma(const __hip_bfloat16* __restrict__ in,
                                                   const __hip_bfloat16* __restrict__ wA,
                                                   const float* __restrict__ bias,
                                                   __hip_bfloat16* __restrict__ out) {
  const int OH = 2 * IH;
  const int NT = IH / 32;
  int n = blockIdx.z;
  int co0 = blockIdx.y * 64;
  int m = blockIdx.x / NT;
  int n0x = (blockIdx.x % NT) * 32;
  int tid = threadIdx.x;
  int w = tid >> 6, lane = tid & 63, fr = lane & 15, kg = lane >> 4;

  __shared__ __align__(16) ushort Wt[4][64][40];
  __shared__ __align__(16) ushort Bt[4][32][40];
  __shared__ ushort patch[8][3][36];

  v4f acc[4][2];
#pragma unroll
  for (int p = 0; p < 4; ++p)
#pragma unroll
    for (int h = 0; h < 2; ++h) acc[p][h] = (v4f){0.f, 0.f, 0.f, 0.f};

  const ushort* inb = (const ushort*)in + (size_t)n * CI * IH * IH;
  const ushort* wab = (const ushort*)wA;

  for (int t = tid; t < 8 * 3 * 36; t += 256) (&patch[0][0][0])[t] = 0;

  int pgoff[4], ploff[4];
  unsigned pmask = 0;
#pragma unroll
  for (int i = 0; i < 4; ++i) {
    int t = tid + 256 * i;
    if (t < 816) {
      int ci = t / 102;
      int rem = t - ci * 102;
      int r = rem / 34;
      int c = rem - r * 34;
      int iy = m - 1 + r, ix = n0x - 1 + c;
      if (iy >= 0 && iy < IH && ix >= 0 && ix < IH) {
        pmask |= 1u << i;
        pgoff[i] = (ci * IH + iy) * IH + ix;
        ploff[i] = (ci * 3 + r) * 36 + c;
      }
    }
  }

  for (int ci0 = 0; ci0 < CI; ci0 += 8) {
    __syncthreads();
    {
      const ushort* ip = inb + (size_t)ci0 * IH * IH;
      ushort* pb = &patch[0][0][0];
#pragma unroll
      for (int i = 0; i < 4; ++i)
        if (pmask & (1u << i)) pb[ploff[i]] = ip[pgoff[i]];
    }
#pragma unroll
    for (int i = 0; i < 4; ++i) {
      int u = tid + 256 * i;
      int kgg = u & 3, co = (u >> 2) & 63, par = u >> 8;
      const uint4 v =
          *(const uint4*)(wab + (((size_t)par * CO + co0 + co) * CI + ci0) * 4 + kgg * 8);
      *(uint4*)&Wt[par][co][kgg * 8] = v;
    }
    __syncthreads();
    {
      int pr = tid >> 1;
      int px0 = (tid & 1) * 16;
      int par = pr >> 5, k = pr & 31;
      int ci = k >> 2, a = (k >> 1) & 1, b = k & 1, ry = par >> 1, rx = par & 1;
      const ushort* src = &patch[ci][ry + a][px0 + rx + b];
      ushort* dst = &Bt[par][px0][k];
#pragma unroll
      for (int p = 0; p < 16; ++p) dst[p * 40] = src[p];
    }
    __syncthreads();
#pragma unroll
    for (int par = 0; par < 4; ++par) {
      v8s af = *(const v8s*)&Wt[par][w * 16 + fr][kg * 8];
      v8s b0 = *(const v8s*)&Bt[par][fr][kg * 8];
      v8s b1 = *(const v8s*)&Bt[par][16 + fr][kg * 8];
      acc[par][0] = __builtin_amdgcn_mfma_f32_16x16x32_bf16(af, b0, acc[par][0], 0, 0, 0);
      acc[par][1] = __builtin_amdgcn_mfma_f32_16x16x32_bf16(af, b1, acc[par][1], 0, 0, 0);
    }
  }
  __hip_bfloat16* ob = out + (size_t)n * CO * OH * OH;
#pragma unroll
  for (int par = 0; par < 4; ++par) {
    int ry = par >> 1, rx = par & 1;
    int oy = 2 * m + ry;
#pragma unroll
    for (int h = 0; h < 2; ++h) {
      int ox = 2 * (n0x + h * 16 + fr) + rx;
#pragma unroll
      for (int r = 0; r < 4; ++r) {
        int co = co0 + w * 16 + kg * 4 + r;
        float val = acc[par][h][r] + bias[co];
        val = fmaxf(val, 0.f);
        ob[((size_t)co * OH + oy) * OH + ox] = __float2bfloat16(val);
      }
    }
  }
}

// ---- D4: conv 64->1, 3x3, s1, p1, sigmoid; bf16 input (R13 16x16 form) ----
__global__ __launch_bounds__(256) void k_conv_out(const __hip_bfloat16* __restrict__ in,
                                                  const float* __restrict__ w,
                                                  const float* __restrict__ bias,
                                                  float* __restrict__ out) {
  int n = blockIdx.z;
  int tile = blockIdx.x;
  int TY0 = (tile / 16) * 16, TX0 = (tile % 16) * 16;
  int ty = threadIdx.x >> 4, tx = threadIdx.x & 15;
  __shared__ float sm[2][18 * 18];
  float acc = bias[0];
  const __hip_bfloat16* inb = in + (size_t)n * 64 * 65536;
  int goff[2], loff[2];
  unsigned vmask = 0;
#pragma unroll
  for (int i = 0; i < 2; ++i) {
    int t = threadIdx.x + 256 * i;
    if (t < 324) {
      int r = t / 18, c = t - r * 18;
      int iy = TY0 - 1 + r, ix = TX0 - 1 + c;
      if (iy >= 0 && iy < 256 && ix >= 0 && ix < 256) {
        vmask |= 1u << i;
        goff[i] = iy * 256 + ix;
        loff[i] = t;
      }
    }
  }
  for (int t = threadIdx.x; t < 2 * 324; t += 256) (&sm[0][0])[t] = 0.f;
  __syncthreads();
  auto stage = [&](int buf, int ci) {
    const __hip_bfloat16* ip = inb + (size_t)ci * 65536;
    float* dst = sm[buf];
#pragma unroll
    for (int i = 0; i < 2; ++i)
      if (vmask & (1u << i)) dst[loff[i]] = __bfloat162float(ip[goff[i]]);
  };
  stage(0, 0);
  for (int ci = 0; ci < 64; ++ci) {
    int buf = ci & 1;
    __syncthreads();
    if (ci + 1 < 64) stage(buf ^ 1, ci + 1);
    const float* wp = w + ci * 9;
#pragma unroll
    for (int dy = 0; dy < 3; ++dy)
#pragma unroll
      for (int dx = 0; dx < 3; ++dx) acc += sm[buf][(ty + dy) * 18 + tx + dx] * wp[dy * 3 + dx];
  }
  out[(size_t)n * 65536 + (TY0 + ty) * 256 + TX0 + tx] = 1.f / (1.f + expf(-acc));
}

extern "C" void kernel_launch(void* const* d_in, const int* in_sizes, int n_in,
                              void* d_out, int out_size, void* d_ws, size_t ws_size,
                              hipStream_t stream) {
  const float* x = (const float*)d_in[0];
  const float* ew1 = (const float*)d_in[1];
  const float* eb1 = (const float*)d_in[2];
  const float* ew2 = (const float*)d_in[3];
  const float* eb2 = (const float*)d_in[4];
  const float* ew3 = (const float*)d_in[5];
  const float* eb3 = (const float*)d_in[6];
  const float* ew4 = (const float*)d_in[7];
  const float* eb4 = (const float*)d_in[8];
  const float* cb = (const float*)d_in[9];
  const float* dw1 = (const float*)d_in[10];
  const float* db1 = (const float*)d_in[11];
  const float* dw2 = (const float*)d_in[12];
  const float* db2 = (const float*)d_in[13];
  const float* dw3 = (const float*)d_in[14];
  const float* db3 = (const float*)d_in[15];
  const float* dw4 = (const float*)d_in[16];
  const float* db4 = (const float*)d_in[17];

  float* ws = (float*)d_ws;
  // Region A [0, 33554432): z | A-tail scratch | d3bf (first 16.7M floats)
  // Region Bb [33554432, 50331648): h2 -> d2bf
  // Region Cc [50331648, 58720256): h3 -> d1bf
  float* A = ws;
  float* Bb = ws + 33554432;
  float* Cc = ws + 50331648;
  float* cn = A + 16777216;                                   // 1024
  float* xn = A + 16778240;                                   // 32768
  int* idx = (int*)(A + 16811008);                            // 32768 ints
  __hip_bfloat16* zqbf = (__hip_bfloat16*)(A + 20971520);     // 8,388,608 bf16
  __hip_bfloat16* wbfA2 = (__hip_bfloat16*)(A + 25165824);    // 524,288 bf16
  __hip_bfloat16* wbfA3 = (__hip_bfloat16*)(A + 25427968);    // 131,072 bf16
  __hip_bfloat16* wbf1 = (__hip_bfloat16*)(A + 25493504);     // 65,536 bf16
  __hip_bfloat16* d1bf = (__hip_bfloat16*)Cc;                 // 8,388,608 bf16
  __hip_bfloat16* d2bf = (__hip_bfloat16*)Bb;                 // 16,777,216 bf16
  __hip_bfloat16* d3bf = (__hip_bfloat16*)A;                  // 33,554,432 bf16

  float* recon = (float*)d_out;               // 524,288
  float* zq = recon + 524288;                 // 8,388,608
  float* idxf = zq + 8388608;                 // 32,768

  // encoder (fp32, bit-frozen chains)
  k_conv12<<<dim3(64, 4, NB), 256, 0, stream>>>(x, ew1, eb1, ew2, eb2, Bb);
  k_conv3s2<128, 128><<<dim3(16, 8, NB), 256, 0, stream>>>(Bb, ew3, eb3, Cc, 256);
  k_conv1x1<<<dim3(16, 32, NB), 256, 0, stream>>>(Cc, ew4, eb4, A, 256, 256, 4096);
  // decoder weight transforms
  k_wconv<<<2048, 256, 0, stream>>>(dw2, wbfA2, 256, 128);
  k_wconv<<<512, 256, 0, stream>>>(dw3, wbfA3, 128, 64);
  k_wconv1<<<256, 256, 0, stream>>>(dw1, wbf1);
  // VQ (np-fp32-faithful)
  k_cnorm<<<4, 256, 0, stream>>>(cb, cn);
  k_xnorm<<<128, 256, 0, stream>>>(A, xn);
  k_vq<<<512, 256, 0, stream>>>(A, cb, cn, xn, idx, idxf);
  k_gather<<<8192, 256, 0, stream>>>(idx, cb, zq, zqbf);
  // decoder (bf16 MFMA; reads only ws buffers)
  k_d1mfma<<<dim3(64, 4, NB), 256, 0, stream>>>(zqbf, wbf1, db1, d1bf);
  k_convTmfma<256, 64, 128><<<dim3(128, 2, NB), 256, 0, stream>>>(d1bf, wbfA2, db2, d2bf);
  k_convTmfma<128, 128, 64><<<dim3(512, 1, NB), 256, 0, stream>>>(d2bf, wbfA3, db3, d3bf);
  k_conv_out<<<dim3(256, 1, NB), 256, 0, stream>>>(d3bf, dw4, db4, recon);
}